// Round 1
// baseline (71.236 us; speedup 1.0000x reference)
//
#include <hip/hip_runtime.h>
#include <hip/hip_bf16.h>

// ---------------- types ----------------
typedef __bf16 bf16x8 __attribute__((ext_vector_type(8)));
typedef float  f32x4  __attribute__((ext_vector_type(4)));

// ---------------- problem constants ----------------
#define BATCH 128
#define NSOL  1027
#define IND   257           // input dim
#define EMB   256           // output dim
// output segment offsets (floats)
#define OUT_SRC  0ULL
#define OUT_CAND 32768ULL
#define OUT_DST  33587200ULL
#define OUT_DEP  33619968ULL

// workspace layout (bytes)
#define WFRAG_OFF 0          // cand W_eff, bf16, MFMA-B-fragment order: [kk(9)][ntg(16)][lane(64)][j(8)]
#define BEFF_OFF  147456     // b_eff fp32 [4][256]  (seg order: src,cand,dst,dep)
#define WT_OFF    151552     // W_eff fp32 [4][257][256] ([seg][k][e], e fastest)

__device__ __forceinline__ void gload_lds16(const void* g, void* l) {
    __builtin_amdgcn_global_load_lds((const __attribute__((address_space(1))) void*)g,
                                     (__attribute__((address_space(3))) void*)l,
                                     16, 0, 0);
}

// ---------------- prep: build effective weights ----------------
__global__ __launch_bounds__(256) void swne_prep(
    const float* __restrict__ Wsrc, const float* __restrict__ bsrc,
    const float* __restrict__ Wdst, const float* __restrict__ bdst,
    const float* __restrict__ Wdep, const float* __restrict__ bdep,
    const float* __restrict__ Wcand, const float* __restrict__ bcand,
    const float* __restrict__ Wreg, const float* __restrict__ breg,
    const float* __restrict__ Wrand, const float* __restrict__ iw,
    char* __restrict__ ws)
{
    const float a  = 1.0f / (1.0f + expf(-iw[0]));   // sigmoid(integration_weight)
    const float ca = 1.0f - a;
    const float sa = 0.1f * a;

    const float* Ws[4] = {Wsrc, Wcand, Wdst, Wdep};
    const float* Bs[4] = {bsrc, bcand, bdst, bdep};

    const int gid = blockIdx.x * 256 + threadIdx.x;
    const int gsz = gridDim.x * 256;

    // b_eff [4][256]
    float* beff = (float*)(ws + BEFF_OFF);
    for (int i = gid; i < 4 * EMB; i += gsz) {
        int seg = i >> 8, e = i & 255;
        beff[i] = ca * Bs[seg][e] + a * breg[e];
    }

    // W_eff transposed fp32 [4][257][256]
    float* wt = (float*)(ws + WT_OFF);
    for (int i = gid; i < 4 * IND * EMB; i += gsz) {
        int seg = i / (IND * EMB);
        int rem = i - seg * (IND * EMB);
        int k = rem >> 8, e = rem & 255;
        int si = e * IND + k;
        wt[i] = ca * Ws[seg][si] + a * Wreg[si] + sa * Wrand[si];
    }

    // cand W_eff bf16 in MFMA B-fragment order, K padded 257->288 with zeros
    __bf16* wfr = (__bf16*)(ws + WFRAG_OFF);
    for (int i = gid; i < 9 * 16 * 64 * 8; i += gsz) {
        int kk   = i >> 13;          // /8192
        int rem  = i & 8191;
        int ntg  = rem >> 9;         // /512
        int rem2 = rem & 511;
        int l    = rem2 >> 3;
        int j    = rem2 & 7;
        int e = ntg * 16 + (l & 15);
        int k = kk * 32 + (l >> 4) * 8 + j;
        float v = 0.0f;
        if (k < IND) {
            int si = e * IND + k;
            v = ca * Wcand[si] + a * Wreg[si] + sa * Wrand[si];
        }
        wfr[i] = (__bf16)v;
    }
}

// ---------------- main: 384 edge blocks + 4096 cand MFMA blocks ----------------
__global__ __launch_bounds__(256) void swne_main(const float* __restrict__ sol,
                                                 const char* __restrict__ ws,
                                                 float* __restrict__ out)
{
    __shared__ float lds_a[8448];     // 33 KiB: 32 rows x 257 f32 staged raw (+align slack)
    const int tid = threadIdx.x;
    const int bid = blockIdx.x;
    const float* beff = (const float*)(ws + BEFF_OFF);

    if (bid < 384) {
        // ---- edge rows: src / dst / dep, one row per block, fp32 ----
        int s = bid >> 7;            // 0:src 1:dst 2:dep
        int b = bid & 127;
        int nrow  = (s == 0) ? 0 : (s == 1 ? 1025 : 1026);
        int segw  = (s == 0) ? 0 : (s == 1 ? 2 : 3);
        size_t outb = (s == 0) ? OUT_SRC : (s == 1 ? OUT_DST : OUT_DEP);
        const float* x = sol + (size_t)(b * NSOL + nrow) * IND;
        for (int i = tid; i < IND; i += 256) lds_a[i] = x[i];
        __syncthreads();
        const float* wtp = (const float*)(ws + WT_OFF) + (size_t)segw * (IND * EMB) + tid;
        float s0 = 0.f, s1 = 0.f, s2 = 0.f, s3 = 0.f;
        #pragma unroll 4
        for (int k = 0; k < 256; k += 4) {
            s0 = fmaf(lds_a[k + 0], wtp[(size_t)(k + 0) * 256], s0);
            s1 = fmaf(lds_a[k + 1], wtp[(size_t)(k + 1) * 256], s1);
            s2 = fmaf(lds_a[k + 2], wtp[(size_t)(k + 2) * 256], s2);
            s3 = fmaf(lds_a[k + 3], wtp[(size_t)(k + 3) * 256], s3);
        }
        float sum = beff[segw * 256 + tid] + ((s0 + s1) + (s2 + s3))
                  + lds_a[256] * wtp[(size_t)256 * 256];
        out[outb + (size_t)b * 256 + tid] = sum;
        return;
    }

    // ---- candidate rows: 32-row x 256-col MFMA tile per block ----
    const int cbid = bid - 384;
    const int bb = cbid >> 5;        // batch
    const int t  = cbid & 31;        // 32-row tile within the 1024 cand rows
    const size_t base_byte = (size_t)(bb * NSOL + 1 + t * 32) * IND * 4;
    const size_t S0 = base_byte & ~(size_t)15;      // 16B-aligned staging start
    const int h = (int)((base_byte - S0) >> 2);     // 0..3 dword shift

    const int lane = tid & 63, wave = tid >> 6;

    // stage 33 KiB of raw fp32 rows into LDS (contiguous; over-read <=896B is in-bounds)
    for (int c = wave; c < 33; c += 4)
        gload_lds16((const char*)sol + S0 + (size_t)c * 1024 + (size_t)lane * 16,
                    (char*)lds_a + c * 1024);
    __syncthreads();

    f32x4 acc[2][4];
    #pragma unroll
    for (int rt = 0; rt < 2; ++rt)
        #pragma unroll
        for (int nt = 0; nt < 4; ++nt) {
            f32x4 z = {0.f, 0.f, 0.f, 0.f};
            acc[rt][nt] = z;
        }

    const int rl = lane & 15, grp = lane >> 4;
    const bf16x8* wf8 = (const bf16x8*)(ws + WFRAG_OFF);
    const int ntb = wave * 4;        // this wave owns cols [wave*64, wave*64+64)

    #pragma unroll
    for (int kk = 0; kk < 9; ++kk) {
        bf16x8 af[2];
        #pragma unroll
        for (int rt = 0; rt < 2; ++rt) {
            const float* ap = &lds_a[h + (rt * 16 + rl) * IND + kk * 32 + grp * 8];
            bf16x8 v;
            #pragma unroll
            for (int j = 0; j < 8; ++j) v[j] = (__bf16)ap[j];
            af[rt] = v;
        }
        #pragma unroll
        for (int nt = 0; nt < 4; ++nt) {
            bf16x8 bv = wf8[(size_t)(kk * 16 + ntb + nt) * 64 + lane];
            #pragma unroll
            for (int rt = 0; rt < 2; ++rt)
                acc[rt][nt] = __builtin_amdgcn_mfma_f32_16x16x32_bf16(af[rt], bv, acc[rt][nt], 0, 0, 0);
        }
    }

    float bvals[4];
    #pragma unroll
    for (int nt = 0; nt < 4; ++nt)
        bvals[nt] = beff[256 + wave * 64 + nt * 16 + rl];   // seg 1 = cand

    float* outc = out + OUT_CAND + (size_t)(bb * 1024 + t * 32) * 256 + wave * 64 + rl;
    #pragma unroll
    for (int rt = 0; rt < 2; ++rt)
        #pragma unroll
        for (int nt = 0; nt < 4; ++nt)
            #pragma unroll
            for (int i = 0; i < 4; ++i) {
                int row = rt * 16 + grp * 4 + i;
                outc[(size_t)row * 256 + nt * 16] = acc[rt][nt][i] + bvals[nt];
            }
}

extern "C" void kernel_launch(void* const* d_in, const int* in_sizes, int n_in,
                              void* d_out, int out_size, void* d_ws, size_t ws_size,
                              hipStream_t stream) {
    const float* sol   = (const float*)d_in[0];
    const float* Wsrc  = (const float*)d_in[1];
    const float* bsrc  = (const float*)d_in[2];
    const float* Wdst  = (const float*)d_in[3];
    const float* bdst  = (const float*)d_in[4];
    const float* Wdep  = (const float*)d_in[5];
    const float* bdep  = (const float*)d_in[6];
    const float* Wcand = (const float*)d_in[7];
    const float* bcand = (const float*)d_in[8];
    const float* Wreg  = (const float*)d_in[9];
    const float* breg  = (const float*)d_in[10];
    const float* Wrand = (const float*)d_in[11];
    const float* iw    = (const float*)d_in[12];

    swne_prep<<<512, 256, 0, stream>>>(Wsrc, bsrc, Wdst, bdst, Wdep, bdep,
                                       Wcand, bcand, Wreg, breg, Wrand, iw,
                                       (char*)d_ws);
    swne_main<<<4480, 256, 0, stream>>>(sol, (const char*)d_ws, (float*)d_out);
}